// Round 2
// baseline (183.741 us; speedup 1.0000x reference)
//
#include <hip/hip_runtime.h>
#include <hip/hip_bf16.h>

#define B_  16384
#define I_  512
#define H1_ 256
#define H2_ 128
#define E_  8
#define T_  2

typedef __attribute__((ext_vector_type(8))) short short8;
typedef __attribute__((ext_vector_type(4))) float float4_t;

__device__ inline unsigned short f2bf(float f) {
    union { float f; unsigned u; } v; v.f = f;
    unsigned r = v.u + 0x7FFFu + ((v.u >> 16) & 1u);
    return (unsigned short)(r >> 16);
}

// async global->LDS, 16B per lane. LDS dest = wave-uniform base + lane*16.
__device__ inline void async_copy16(const unsigned short* g, unsigned short* l) {
    __builtin_amdgcn_global_load_lds(
        (const __attribute__((address_space(1))) void*)g,
        (__attribute__((address_space(3))) void*)l,
        16, 0, 0);
}

// ---------------- prep: x fp32 -> bf16 ----------------
__global__ void conv_x_kernel(const float* __restrict__ x, unsigned short* __restrict__ xb) {
    int idx = blockIdx.x * 256 + threadIdx.x;   // one thread per 8 elements
    size_t base = (size_t)idx * 8;
    float4_t a = *(const float4_t*)(x + base);
    float4_t b = *(const float4_t*)(x + base + 4);
    short8 s;
    s[0] = (short)f2bf(a[0]); s[1] = (short)f2bf(a[1]);
    s[2] = (short)f2bf(a[2]); s[3] = (short)f2bf(a[3]);
    s[4] = (short)f2bf(b[0]); s[5] = (short)f2bf(b[1]);
    s[6] = (short)f2bf(b[2]); s[7] = (short)f2bf(b[3]);
    *(short8*)(xb + base) = s;
}

// ---------------- prep: transpose [E][R][C] fp32 -> [E][C][R] bf16 ----------------
__global__ void transpose_bf16_kernel(const float* __restrict__ in, unsigned short* __restrict__ out,
                                      int R, int C) {
    __shared__ float tile[32][33];
    int e = blockIdx.z;
    int c0 = blockIdx.x * 32;
    int r0 = blockIdx.y * 32;
    const float* inp = in + (size_t)e * R * C;
    unsigned short* outp = out + (size_t)e * R * C;
    int tx = threadIdx.x, ty = threadIdx.y;   // (32, 8)
#pragma unroll
    for (int j = 0; j < 32; j += 8)
        tile[ty + j][tx] = inp[(size_t)(r0 + ty + j) * C + c0 + tx];
    __syncthreads();
#pragma unroll
    for (int j = 0; j < 32; j += 8)
        outp[(size_t)(c0 + ty + j) * R + r0 + tx] = f2bf(tile[tx][ty + j]);
}

// ---------------- prep: Wg [T][I][E] fp32 -> WgT [T*E][I] bf16 ----------------
__global__ void prep_wgt_kernel(const float* __restrict__ wg, unsigned short* __restrict__ wgt) {
    int idx = blockIdx.x * 256 + threadIdx.x;  // 16*512 = 8192
    int te = idx >> 9;
    int i  = idx & 511;
    int t = te >> 3, e = te & 7;
    wgt[(size_t)te * I_ + i] = f2bf(wg[(size_t)t * I_ * E_ + (size_t)i * E_ + e]);
}

// ---------------- gates: [B,512]x[512,16] MFMA GEMM + softmax over e ----------------
// output layout: gates[T*E][B] fp32 (plane-major for coalesced combine-side reads)
__global__ void gates_kernel(const unsigned short* __restrict__ xb,
                             const unsigned short* __restrict__ wgt,
                             const float* __restrict__ bg,
                             float* __restrict__ gates) {
    int w = threadIdx.x >> 6, lane = threadIdx.x & 63;
    int row0 = (blockIdx.x * 4 + w) * 16;
    int col = lane & 15, quad = lane >> 4;
    float4_t acc = {0.f, 0.f, 0.f, 0.f};
    const unsigned short* aG = xb + (size_t)(row0 + col) * I_ + quad * 8;
    const unsigned short* bG = wgt + (size_t)col * I_ + quad * 8;
#pragma unroll
    for (int k = 0; k < I_; k += 32) {
        short8 a = *(const short8*)(aG + k);
        short8 b = *(const short8*)(bG + k);
        acc = __builtin_amdgcn_mfma_f32_16x16x32_bf16(a, b, acc, 0, 0, 0);
    }
    float bias = bg[col];   // bg is [T][E] flat == [te]
#pragma unroll
    for (int p = 0; p < 4; ++p) {
        float v = acc[p] + bias;
        float m = v;
        m = fmaxf(m, __shfl_xor(m, 1));
        m = fmaxf(m, __shfl_xor(m, 2));
        m = fmaxf(m, __shfl_xor(m, 4));
        float ev = __expf(v - m);
        float s = ev;
        s += __shfl_xor(s, 1);
        s += __shfl_xor(s, 2);
        s += __shfl_xor(s, 4);
        gates[(size_t)col * B_ + row0 + quad * 4 + p] = ev / s;
    }
}

// ---------------- layer 1 grouped GEMM: h[e] = relu(xb * w1t[e]^T + b1[e]) bf16 ----------------
// 128x128 tile, BK=64, 4 waves of 64x64, 16x16x32 MFMA, XOR-swizzled LDS.
__global__ void gemm_relu_kernel(const unsigned short* __restrict__ A, size_t aSE,
                                 const unsigned short* __restrict__ Bt, size_t bSE,
                                 const float* __restrict__ bias, int biasSE,
                                 unsigned short* __restrict__ C, size_t cSE,
                                 int K, int lda, int ldb, int ldc) {
    __shared__ unsigned short As[128 * 64];
    __shared__ unsigned short Bs[128 * 64];
    int e = blockIdx.z;
    const unsigned short* Ae = A + (size_t)e * aSE;
    const unsigned short* Be = Bt + (size_t)e * bSE;
    const float* biasE = bias + (size_t)e * biasSE;
    unsigned short* Ce = C + (size_t)e * cSE;
    int m0 = blockIdx.x * 128, n0 = blockIdx.y * 128;
    int t = threadIdx.x, w = t >> 6, lane = t & 63;
    int col = lane & 15, quad = lane >> 4;
    int wm = (w & 1) * 64, wn = (w >> 1) * 64;

    float4_t acc[4][4];
#pragma unroll
    for (int mi = 0; mi < 4; ++mi)
#pragma unroll
        for (int ni = 0; ni < 4; ++ni)
            acc[mi][ni] = (float4_t){0.f, 0.f, 0.f, 0.f};

    int rT = t >> 3;
    int gk = (((t & 7) ^ (rT & 7))) * 8;
    const unsigned short* aG = Ae + (size_t)(m0 + rT) * lda + gk;
    const unsigned short* bG = Be + (size_t)(n0 + rT) * ldb + gk;
    unsigned short* aL = As + (size_t)w * 64 * 8;
    unsigned short* bL = Bs + (size_t)w * 64 * 8;

    for (int k0 = 0; k0 < K; k0 += 64) {
#pragma unroll
        for (int j = 0; j < 4; ++j) {
            async_copy16(aG + (size_t)j * 32 * lda + k0, aL + j * 2048);
            async_copy16(bG + (size_t)j * 32 * ldb + k0, bL + j * 2048);
        }
        __syncthreads();
#pragma unroll
        for (int kk = 0; kk < 64; kk += 32) {
            int q = (kk >> 3) + quad;
            short8 af[4], bf[4];
#pragma unroll
            for (int mi = 0; mi < 4; ++mi) {
                int r = wm + mi * 16 + col;
                af[mi] = *(const short8*)&As[r * 64 + ((q ^ (r & 7)) * 8)];
            }
#pragma unroll
            for (int ni = 0; ni < 4; ++ni) {
                int r = wn + ni * 16 + col;
                bf[ni] = *(const short8*)&Bs[r * 64 + ((q ^ (r & 7)) * 8)];
            }
#pragma unroll
            for (int mi = 0; mi < 4; ++mi)
#pragma unroll
                for (int ni = 0; ni < 4; ++ni)
                    acc[mi][ni] = __builtin_amdgcn_mfma_f32_16x16x32_bf16(af[mi], bf[ni], acc[mi][ni], 0, 0, 0);
        }
        __syncthreads();
    }

#pragma unroll
    for (int ni = 0; ni < 4; ++ni) {
        int c = n0 + wn + ni * 16 + col;
        float bv = biasE[c];
#pragma unroll
        for (int mi = 0; mi < 4; ++mi) {
            int rbase = m0 + wm + mi * 16 + quad * 4;
#pragma unroll
            for (int p = 0; p < 4; ++p) {
                float v = acc[mi][ni][p] + bv;
                v = v > 0.f ? v : 0.f;
                Ce[(size_t)(rbase + p) * ldc + c] = f2bf(v);
            }
        }
    }
}

// ---------------- fused layer2 + gated combine ----------------
// Per block: 64 rows of B, loops over all 8 experts.
//   eo_e = relu(h[e](64x256) * W2t[e](128x256)^T + b2[e])  via MFMA
//   towers[t] += gates[t][e][b] * eo_e                      in registers
// Writes out [T][B][H2] fp32 once. Eliminates eo materialization.
__global__ void fused_l2_combine_kernel(const unsigned short* __restrict__ h,
                                        const unsigned short* __restrict__ w2t,
                                        const float* __restrict__ b2,
                                        const float* __restrict__ gates,
                                        float* __restrict__ out) {
    __shared__ unsigned short As[64 * 64];    //  8KB: h tile (64 rows x 64 k)
    __shared__ unsigned short Bs[128 * 64];   // 16KB: W2t tile (128 n x 64 k)
    __shared__ float gL[16 * 64];             //  4KB: gates [te][64 rows]

    int b0 = blockIdx.x * 64;
    int t = threadIdx.x, w = t >> 6, lane = t & 63;
    int col = lane & 15, quad = lane >> 4;
    int wn = w * 32;                           // 4 waves x 32 cols = 128 cols

    // stage gates for this row slab: 16 te-planes x 64 rows
    {
        int te = t >> 4, i4 = (t & 15) * 4;
        *(float4_t*)&gL[te * 64 + i4] = *(const float4_t*)&gates[(size_t)te * B_ + b0 + i4];
    }

    float4_t tw0[4][2], tw1[4][2];
#pragma unroll
    for (int mi = 0; mi < 4; ++mi)
#pragma unroll
        for (int ni = 0; ni < 2; ++ni) {
            tw0[mi][ni] = (float4_t){0.f, 0.f, 0.f, 0.f};
            tw1[mi][ni] = (float4_t){0.f, 0.f, 0.f, 0.f};
        }

    int rT = t >> 3;
    int slot = t & 7;

    for (int e = 0; e < E_; ++e) {
        const unsigned short* hE = h + (size_t)e * B_ * H1_;
        const unsigned short* w2E = w2t + (size_t)e * H2_ * H1_;

        float4_t acc[4][2];
#pragma unroll
        for (int mi = 0; mi < 4; ++mi)
#pragma unroll
            for (int ni = 0; ni < 2; ++ni)
                acc[mi][ni] = (float4_t){0.f, 0.f, 0.f, 0.f};

        for (int k0 = 0; k0 < H1_; k0 += 64) {
            // stage h tile: rows b0..b0+63, 2 issues
#pragma unroll
            for (int j = 0; j < 2; ++j) {
                int row = j * 32 + rT;
                int gk = (slot ^ (row & 7)) * 8;
                async_copy16(hE + (size_t)(b0 + row) * H1_ + k0 + gk,
                             As + j * 2048 + w * 512);
            }
            // stage W2t tile: rows 0..127, 4 issues
#pragma unroll
            for (int j = 0; j < 4; ++j) {
                int row = j * 32 + rT;
                int gk = (slot ^ (row & 7)) * 8;
                async_copy16(w2E + (size_t)row * H1_ + k0 + gk,
                             Bs + j * 2048 + w * 512);
            }
            __syncthreads();
#pragma unroll
            for (int kk = 0; kk < 64; kk += 32) {
                int q = (kk >> 3) + quad;
                short8 af[4], bfr[2];
#pragma unroll
                for (int mi = 0; mi < 4; ++mi) {
                    int r = mi * 16 + col;
                    af[mi] = *(const short8*)&As[r * 64 + ((q ^ (r & 7)) * 8)];
                }
#pragma unroll
                for (int ni = 0; ni < 2; ++ni) {
                    int r = wn + ni * 16 + col;
                    bfr[ni] = *(const short8*)&Bs[r * 64 + ((q ^ (r & 7)) * 8)];
                }
#pragma unroll
                for (int mi = 0; mi < 4; ++mi)
#pragma unroll
                    for (int ni = 0; ni < 2; ++ni)
                        acc[mi][ni] = __builtin_amdgcn_mfma_f32_16x16x32_bf16(af[mi], bfr[ni], acc[mi][ni], 0, 0, 0);
            }
            __syncthreads();
        }

        // bias + relu + gated accumulate
        float bv0 = b2[e * H2_ + wn + col];
        float bv1 = b2[e * H2_ + wn + 16 + col];
#pragma unroll
        for (int mi = 0; mi < 4; ++mi) {
            float4_t g0 = *(const float4_t*)&gL[e * 64 + mi * 16 + quad * 4];        // task 0
            float4_t g1 = *(const float4_t*)&gL[(8 + e) * 64 + mi * 16 + quad * 4];  // task 1
#pragma unroll
            for (int ni = 0; ni < 2; ++ni) {
                float bv = ni == 0 ? bv0 : bv1;
#pragma unroll
                for (int p = 0; p < 4; ++p) {
                    float v = acc[mi][ni][p] + bv;
                    v = v > 0.f ? v : 0.f;
                    tw0[mi][ni][p] += g0[p] * v;
                    tw1[mi][ni][p] += g1[p] * v;
                }
            }
        }
    }

    // write out [T][B][H2]
#pragma unroll
    for (int mi = 0; mi < 4; ++mi) {
#pragma unroll
        for (int ni = 0; ni < 2; ++ni) {
            int n = wn + ni * 16 + col;
#pragma unroll
            for (int p = 0; p < 4; ++p) {
                int r = b0 + mi * 16 + quad * 4 + p;
                out[(size_t)r * H2_ + n] = tw0[mi][ni][p];
                out[(size_t)B_ * H2_ + (size_t)r * H2_ + n] = tw1[mi][ni][p];
            }
        }
    }
}

extern "C" void kernel_launch(void* const* d_in, const int* in_sizes, int n_in,
                              void* d_out, int out_size, void* d_ws, size_t ws_size,
                              hipStream_t stream) {
    const float* x  = (const float*)d_in[0];
    const float* W1 = (const float*)d_in[1];
    const float* b1 = (const float*)d_in[2];
    const float* W2 = (const float*)d_in[3];
    const float* b2 = (const float*)d_in[4];
    const float* Wg = (const float*)d_in[5];
    const float* bg = (const float*)d_in[6];
    float* out = (float*)d_out;

    char* ws = (char*)d_ws;
    unsigned short* xb    = (unsigned short*)(ws);                // 16,777,216 B
    unsigned short* w1t   = (unsigned short*)(ws + 16777216);     //  2,097,152 B
    unsigned short* w2t   = (unsigned short*)(ws + 18874368);     //    524,288 B
    unsigned short* wgt   = (unsigned short*)(ws + 19398656);     //     16,384 B
    float*          gates = (float*)(ws + 19415040);              //  1,048,576 B  [16][B]
    unsigned short* h     = (unsigned short*)(ws + 20463616);     // 67,108,864 B
    // total: 87,572,480 B

    // prep
    conv_x_kernel<<<dim3(B_ * I_ / 8 / 256), 256, 0, stream>>>(x, xb);
    transpose_bf16_kernel<<<dim3(H1_ / 32, I_ / 32, E_), dim3(32, 8), 0, stream>>>(W1, w1t, I_, H1_);
    transpose_bf16_kernel<<<dim3(H2_ / 32, H1_ / 32, E_), dim3(32, 8), 0, stream>>>(W2, w2t, H1_, H2_);
    prep_wgt_kernel<<<dim3(T_ * E_ * I_ / 256), 256, 0, stream>>>(Wg, wgt);

    // gates -> [T*E][B]
    gates_kernel<<<dim3(B_ / 64), 256, 0, stream>>>(xb, wgt, bg, gates);

    // layer 1: h[e] = relu(xb * w1t[e]^T + b1[e])   M=B, N=H1, K=I
    gemm_relu_kernel<<<dim3(B_ / 128, H1_ / 128, E_), 256, 0, stream>>>(
        xb, 0, w1t, (size_t)H1_ * I_, b1, H1_, h, (size_t)B_ * H1_, I_, I_, I_, H1_);

    // fused layer 2 + combine
    fused_l2_combine_kernel<<<dim3(B_ / 64), 256, 0, stream>>>(h, w2t, b2, gates, out);
}

// Round 3
// 172.888 us; speedup vs baseline: 1.0628x; 1.0628x over previous
//
#include <hip/hip_runtime.h>
#include <hip/hip_bf16.h>

#define B_  16384
#define I_  512
#define H1_ 256
#define H2_ 128
#define E_  8
#define T_  2

typedef __attribute__((ext_vector_type(8))) short short8;
typedef __attribute__((ext_vector_type(4))) float float4_t;

__device__ inline unsigned short f2bf(float f) {
    union { float f; unsigned u; } v; v.f = f;
    unsigned r = v.u + 0x7FFFu + ((v.u >> 16) & 1u);
    return (unsigned short)(r >> 16);
}

// async global->LDS, 16B per lane. LDS dest = wave-uniform base + lane*16.
__device__ inline void async_copy16(const unsigned short* g, unsigned short* l) {
    __builtin_amdgcn_global_load_lds(
        (const __attribute__((address_space(1))) void*)g,
        (__attribute__((address_space(3))) void*)l,
        16, 0, 0);
}

// ---------------- prep: transpose [E][R][C] fp32 -> [E][C][R] bf16 ----------------
__global__ void transpose_bf16_kernel(const float* __restrict__ in, unsigned short* __restrict__ out,
                                      int R, int C) {
    __shared__ float tile[32][33];
    int e = blockIdx.z;
    int c0 = blockIdx.x * 32;
    int r0 = blockIdx.y * 32;
    const float* inp = in + (size_t)e * R * C;
    unsigned short* outp = out + (size_t)e * R * C;
    int tx = threadIdx.x, ty = threadIdx.y;   // (32, 8)
#pragma unroll
    for (int j = 0; j < 32; j += 8)
        tile[ty + j][tx] = inp[(size_t)(r0 + ty + j) * C + c0 + tx];
    __syncthreads();
#pragma unroll
    for (int j = 0; j < 32; j += 8)
        outp[(size_t)(c0 + ty + j) * R + r0 + tx] = f2bf(tile[tx][ty + j]);
}

// ---------------- prep: Wg [T][I][E] fp32 -> WgT [T*E][I] bf16 ----------------
__global__ void prep_wgt_kernel(const float* __restrict__ wg, unsigned short* __restrict__ wgt) {
    int idx = blockIdx.x * 256 + threadIdx.x;  // 16*512 = 8192
    int te = idx >> 9;
    int i  = idx & 511;
    int t = te >> 3, e = te & 7;
    wgt[(size_t)te * I_ + i] = f2bf(wg[(size_t)t * I_ * E_ + (size_t)i * E_ + e]);
}

// ---------------- fused x->bf16 conversion + gates GEMM + softmax ----------------
// Reads x fp32 (each element exactly once), writes xb bf16, computes
// gates[T*E][B] fp32 via MFMA ([B,512]x[512,16]) + softmax over e.
__global__ void gates_conv_kernel(const float* __restrict__ x,
                                  unsigned short* __restrict__ xb,
                                  const unsigned short* __restrict__ wgt,
                                  const float* __restrict__ bg,
                                  float* __restrict__ gates) {
    int w = threadIdx.x >> 6, lane = threadIdx.x & 63;
    int row0 = (blockIdx.x * 4 + w) * 16;
    int col = lane & 15, quad = lane >> 4;
    float4_t acc = {0.f, 0.f, 0.f, 0.f};
    const float* xr = x + (size_t)(row0 + col) * I_ + quad * 8;
    unsigned short* xbr = xb + (size_t)(row0 + col) * I_ + quad * 8;
    const unsigned short* bG = wgt + (size_t)col * I_ + quad * 8;
#pragma unroll
    for (int k = 0; k < I_; k += 32) {
        float4_t xa = *(const float4_t*)(xr + k);
        float4_t xc = *(const float4_t*)(xr + k + 4);
        short8 a;
        a[0] = (short)f2bf(xa[0]); a[1] = (short)f2bf(xa[1]);
        a[2] = (short)f2bf(xa[2]); a[3] = (short)f2bf(xa[3]);
        a[4] = (short)f2bf(xc[0]); a[5] = (short)f2bf(xc[1]);
        a[6] = (short)f2bf(xc[2]); a[7] = (short)f2bf(xc[3]);
        *(short8*)(xbr + k) = a;
        short8 b = *(const short8*)(bG + k);
        acc = __builtin_amdgcn_mfma_f32_16x16x32_bf16(a, b, acc, 0, 0, 0);
    }
    float bias = bg[col];   // bg is [T][E] flat == [te]
#pragma unroll
    for (int p = 0; p < 4; ++p) {
        float v = acc[p] + bias;
        float m = v;
        m = fmaxf(m, __shfl_xor(m, 1));
        m = fmaxf(m, __shfl_xor(m, 2));
        m = fmaxf(m, __shfl_xor(m, 4));
        float ev = __expf(v - m);
        float s = ev;
        s += __shfl_xor(s, 1);
        s += __shfl_xor(s, 2);
        s += __shfl_xor(s, 4);
        gates[(size_t)col * B_ + row0 + quad * 4 + p] = ev / s;
    }
}

// ---------------- layer 1 grouped GEMM: h[e] = relu(xb * w1t[e]^T + b1[e]) bf16 ----------------
// 128x128 tile, BK=64, 4 waves of 64x64, 16x16x32 MFMA, XOR-swizzled LDS.
__global__ void gemm_relu_kernel(const unsigned short* __restrict__ A, size_t aSE,
                                 const unsigned short* __restrict__ Bt, size_t bSE,
                                 const float* __restrict__ bias, int biasSE,
                                 unsigned short* __restrict__ C, size_t cSE,
                                 int K, int lda, int ldb, int ldc) {
    __shared__ unsigned short As[128 * 64];
    __shared__ unsigned short Bs[128 * 64];
    int e = blockIdx.z;
    const unsigned short* Ae = A + (size_t)e * aSE;
    const unsigned short* Be = Bt + (size_t)e * bSE;
    const float* biasE = bias + (size_t)e * biasSE;
    unsigned short* Ce = C + (size_t)e * cSE;
    int m0 = blockIdx.x * 128, n0 = blockIdx.y * 128;
    int t = threadIdx.x, w = t >> 6, lane = t & 63;
    int col = lane & 15, quad = lane >> 4;
    int wm = (w & 1) * 64, wn = (w >> 1) * 64;

    float4_t acc[4][4];
#pragma unroll
    for (int mi = 0; mi < 4; ++mi)
#pragma unroll
        for (int ni = 0; ni < 4; ++ni)
            acc[mi][ni] = (float4_t){0.f, 0.f, 0.f, 0.f};

    int rT = t >> 3;
    int gk = (((t & 7) ^ (rT & 7))) * 8;
    const unsigned short* aG = Ae + (size_t)(m0 + rT) * lda + gk;
    const unsigned short* bG = Be + (size_t)(n0 + rT) * ldb + gk;
    unsigned short* aL = As + (size_t)w * 64 * 8;
    unsigned short* bL = Bs + (size_t)w * 64 * 8;

    for (int k0 = 0; k0 < K; k0 += 64) {
#pragma unroll
        for (int j = 0; j < 4; ++j) {
            async_copy16(aG + (size_t)j * 32 * lda + k0, aL + j * 2048);
            async_copy16(bG + (size_t)j * 32 * ldb + k0, bL + j * 2048);
        }
        __syncthreads();
#pragma unroll
        for (int kk = 0; kk < 64; kk += 32) {
            int q = (kk >> 3) + quad;
            short8 af[4], bf[4];
#pragma unroll
            for (int mi = 0; mi < 4; ++mi) {
                int r = wm + mi * 16 + col;
                af[mi] = *(const short8*)&As[r * 64 + ((q ^ (r & 7)) * 8)];
            }
#pragma unroll
            for (int ni = 0; ni < 4; ++ni) {
                int r = wn + ni * 16 + col;
                bf[ni] = *(const short8*)&Bs[r * 64 + ((q ^ (r & 7)) * 8)];
            }
#pragma unroll
            for (int mi = 0; mi < 4; ++mi)
#pragma unroll
                for (int ni = 0; ni < 4; ++ni)
                    acc[mi][ni] = __builtin_amdgcn_mfma_f32_16x16x32_bf16(af[mi], bf[ni], acc[mi][ni], 0, 0, 0);
        }
        __syncthreads();
    }

#pragma unroll
    for (int ni = 0; ni < 4; ++ni) {
        int c = n0 + wn + ni * 16 + col;
        float bv = biasE[c];
#pragma unroll
        for (int mi = 0; mi < 4; ++mi) {
            int rbase = m0 + wm + mi * 16 + quad * 4;
#pragma unroll
            for (int p = 0; p < 4; ++p) {
                float v = acc[mi][ni][p] + bv;
                v = v > 0.f ? v : 0.f;
                Ce[(size_t)(rbase + p) * ldc + c] = f2bf(v);
            }
        }
    }
}

// ---------------- fused layer2 + gated combine ----------------
// 32-row slab per block (grid 512 -> 2 blocks/CU), BK=128 (2 K-iters/expert).
// Per block: loop experts e=0..7:
//   eo_e = relu(h[e](32x256) * W2t[e](128x256)^T + b2[e])  via MFMA
//   towers[t] += gates[t][e][b] * eo_e                      in registers
// Writes out [T][B][H2] fp32 once.
__global__ void fused_l2_combine_kernel(const unsigned short* __restrict__ h,
                                        const unsigned short* __restrict__ w2t,
                                        const float* __restrict__ b2,
                                        const float* __restrict__ gates,
                                        float* __restrict__ out) {
    __shared__ unsigned short As[32 * 128];   //  8KB: h tile (32 rows x 128 k)
    __shared__ unsigned short Bs[128 * 128];  // 32KB: W2t tile (128 n x 128 k)
    __shared__ float gL[16 * 32];             //  2KB: gates [te][32 rows]

    int b0 = blockIdx.x * 32;
    int t = threadIdx.x, w = t >> 6, lane = t & 63;
    int col = lane & 15, quad = lane >> 4;
    int wn = w * 32;                           // 4 waves x 32 cols = 128 cols

    if (t < 128) {
        int te = t >> 3, i4 = (t & 7) * 4;
        *(float4_t*)&gL[te * 32 + i4] = *(const float4_t*)&gates[(size_t)te * B_ + b0 + i4];
    }
    // gL first used after first k-loop (contains __syncthreads)

    float4_t tw0[2][2], tw1[2][2];
#pragma unroll
    for (int mi = 0; mi < 2; ++mi)
#pragma unroll
        for (int ni = 0; ni < 2; ++ni) {
            tw0[mi][ni] = (float4_t){0.f, 0.f, 0.f, 0.f};
            tw1[mi][ni] = (float4_t){0.f, 0.f, 0.f, 0.f};
        }

    int rT = t >> 4;        // 16 rows per 256-thread issue
    int slot = t & 15;      // 16 slots x 8 shorts = 128-short row

    for (int e = 0; e < E_; ++e) {
        const unsigned short* hE = h + (size_t)e * B_ * H1_;
        const unsigned short* w2E = w2t + (size_t)e * H2_ * H1_;

        float4_t acc[2][2];
#pragma unroll
        for (int mi = 0; mi < 2; ++mi)
#pragma unroll
            for (int ni = 0; ni < 2; ++ni)
                acc[mi][ni] = (float4_t){0.f, 0.f, 0.f, 0.f};

        for (int k0 = 0; k0 < H1_; k0 += 128) {
            // stage h tile: 32 rows, 2 issues of 16 rows
#pragma unroll
            for (int j = 0; j < 2; ++j) {
                int row = j * 16 + rT;
                int gk = (((slot ^ row) & 7) | (slot & 8)) * 8;
                async_copy16(hE + (size_t)(b0 + row) * H1_ + k0 + gk,
                             As + j * 2048 + w * 512);
            }
            // stage W2t tile: 128 rows, 8 issues of 16 rows
#pragma unroll
            for (int j = 0; j < 8; ++j) {
                int row = j * 16 + rT;
                int gk = (((slot ^ row) & 7) | (slot & 8)) * 8;
                async_copy16(w2E + (size_t)row * H1_ + k0 + gk,
                             Bs + j * 2048 + w * 512);
            }
            __syncthreads();
#pragma unroll
            for (int kk = 0; kk < 128; kk += 32) {
                int q = (kk >> 3) + quad;
                short8 af[2], bfr[2];
#pragma unroll
                for (int mi = 0; mi < 2; ++mi) {
                    int r = mi * 16 + col;
                    int sw = ((q & 8) | ((q ^ r) & 7)) * 8;
                    af[mi] = *(const short8*)&As[r * 128 + sw];
                }
#pragma unroll
                for (int ni = 0; ni < 2; ++ni) {
                    int r = wn + ni * 16 + col;
                    int sw = ((q & 8) | ((q ^ r) & 7)) * 8;
                    bfr[ni] = *(const short8*)&Bs[r * 128 + sw];
                }
#pragma unroll
                for (int mi = 0; mi < 2; ++mi)
#pragma unroll
                    for (int ni = 0; ni < 2; ++ni)
                        acc[mi][ni] = __builtin_amdgcn_mfma_f32_16x16x32_bf16(af[mi], bfr[ni], acc[mi][ni], 0, 0, 0);
            }
            __syncthreads();
        }

        // bias + relu + gated accumulate
#pragma unroll
        for (int mi = 0; mi < 2; ++mi) {
            float4_t g0 = *(const float4_t*)&gL[e * 32 + mi * 16 + quad * 4];        // task 0
            float4_t g1 = *(const float4_t*)&gL[(8 + e) * 32 + mi * 16 + quad * 4];  // task 1
#pragma unroll
            for (int ni = 0; ni < 2; ++ni) {
                float bv = b2[e * H2_ + wn + ni * 16 + col];
#pragma unroll
                for (int p = 0; p < 4; ++p) {
                    float v = acc[mi][ni][p] + bv;
                    v = v > 0.f ? v : 0.f;
                    tw0[mi][ni][p] += g0[p] * v;
                    tw1[mi][ni][p] += g1[p] * v;
                }
            }
        }
    }

    // write out [T][B][H2]
#pragma unroll
    for (int mi = 0; mi < 2; ++mi) {
#pragma unroll
        for (int ni = 0; ni < 2; ++ni) {
            int n = wn + ni * 16 + col;
#pragma unroll
            for (int p = 0; p < 4; ++p) {
                int r = b0 + mi * 16 + quad * 4 + p;
                out[(size_t)r * H2_ + n] = tw0[mi][ni][p];
                out[(size_t)B_ * H2_ + (size_t)r * H2_ + n] = tw1[mi][ni][p];
            }
        }
    }
}

extern "C" void kernel_launch(void* const* d_in, const int* in_sizes, int n_in,
                              void* d_out, int out_size, void* d_ws, size_t ws_size,
                              hipStream_t stream) {
    const float* x  = (const float*)d_in[0];
    const float* W1 = (const float*)d_in[1];
    const float* b1 = (const float*)d_in[2];
    const float* W2 = (const float*)d_in[3];
    const float* b2 = (const float*)d_in[4];
    const float* Wg = (const float*)d_in[5];
    const float* bg = (const float*)d_in[6];
    float* out = (float*)d_out;

    char* ws = (char*)d_ws;
    unsigned short* xb    = (unsigned short*)(ws);                // 16,777,216 B
    unsigned short* w1t   = (unsigned short*)(ws + 16777216);     //  2,097,152 B
    unsigned short* w2t   = (unsigned short*)(ws + 18874368);     //    524,288 B
    unsigned short* wgt   = (unsigned short*)(ws + 19398656);     //     16,384 B
    float*          gates = (float*)(ws + 19415040);              //  1,048,576 B  [16][B]
    unsigned short* h     = (unsigned short*)(ws + 20463616);     // 67,108,864 B
    // total: 87,572,480 B

    // prep
    transpose_bf16_kernel<<<dim3(H1_ / 32, I_ / 32, E_), dim3(32, 8), 0, stream>>>(W1, w1t, I_, H1_);
    transpose_bf16_kernel<<<dim3(H2_ / 32, H1_ / 32, E_), dim3(32, 8), 0, stream>>>(W2, w2t, H1_, H2_);
    prep_wgt_kernel<<<dim3(T_ * E_ * I_ / 256), 256, 0, stream>>>(Wg, wgt);

    // x->bf16 + gates -> [T*E][B]
    gates_conv_kernel<<<dim3(B_ / 64), 256, 0, stream>>>(x, xb, wgt, bg, gates);

    // layer 1: h[e] = relu(xb * w1t[e]^T + b1[e])   M=B, N=H1, K=I
    gemm_relu_kernel<<<dim3(B_ / 128, H1_ / 128, E_), 256, 0, stream>>>(
        xb, 0, w1t, (size_t)H1_ * I_, b1, H1_, h, (size_t)B_ * H1_, I_, I_, I_, H1_);

    // fused layer 2 + combine
    fused_l2_combine_kernel<<<dim3(B_ / 32), 256, 0, stream>>>(h, w2t, b2, gates, out);
}

// Round 4
// 165.071 us; speedup vs baseline: 1.1131x; 1.0474x over previous
//
#include <hip/hip_runtime.h>
#include <hip/hip_bf16.h>

#define B_  16384
#define I_  512
#define H1_ 256
#define H2_ 128
#define E_  8
#define T_  2

typedef __attribute__((ext_vector_type(8))) short short8;
typedef __attribute__((ext_vector_type(4))) float float4_t;

__device__ inline unsigned short f2bf(float f) {
    union { float f; unsigned u; } v; v.f = f;
    unsigned r = v.u + 0x7FFFu + ((v.u >> 16) & 1u);
    return (unsigned short)(r >> 16);
}

// async global->LDS, 16B per lane. LDS dest = wave-uniform base + lane*16.
__device__ inline void async_copy16(const unsigned short* g, unsigned short* l) {
    __builtin_amdgcn_global_load_lds(
        (const __attribute__((address_space(1))) void*)g,
        (__attribute__((address_space(3))) void*)l,
        16, 0, 0);
}

// ---------------- prep: transpose [E][R][C] fp32 -> [E][C][R] bf16 ----------------
__global__ void transpose_bf16_kernel(const float* __restrict__ in, unsigned short* __restrict__ out,
                                      int R, int C) {
    __shared__ float tile[32][33];
    int e = blockIdx.z;
    int c0 = blockIdx.x * 32;
    int r0 = blockIdx.y * 32;
    const float* inp = in + (size_t)e * R * C;
    unsigned short* outp = out + (size_t)e * R * C;
    int tx = threadIdx.x, ty = threadIdx.y;   // (32, 8)
#pragma unroll
    for (int j = 0; j < 32; j += 8)
        tile[ty + j][tx] = inp[(size_t)(r0 + ty + j) * C + c0 + tx];
    __syncthreads();
#pragma unroll
    for (int j = 0; j < 32; j += 8)
        outp[(size_t)(c0 + ty + j) * R + r0 + tx] = f2bf(tile[tx][ty + j]);
}

// ---------------- prep: Wg [T][I][E] fp32 -> WgT [T*E][I] bf16 ----------------
__global__ void prep_wgt_kernel(const float* __restrict__ wg, unsigned short* __restrict__ wgt) {
    int idx = blockIdx.x * 256 + threadIdx.x;  // 16*512 = 8192
    int te = idx >> 9;
    int i  = idx & 511;
    int t = te >> 3, e = te & 7;
    wgt[(size_t)te * I_ + i] = f2bf(wg[(size_t)t * I_ * E_ + (size_t)i * E_ + e]);
}

// ---------------- fused x->bf16 + gates (split-K MFMA) + softmax ----------------
// Block = 16 rows of B; 4 waves each own a K-quarter (128). Partial 16x16 tiles
// LDS-reduced, per-thread softmax over e. Grid B/16 = 1024 -> 16 waves/CU.
__global__ void gates_split_kernel(const float* __restrict__ x,
                                   unsigned short* __restrict__ xb,
                                   const unsigned short* __restrict__ wgt,
                                   const float* __restrict__ bg,
                                   float* __restrict__ gates) {
    __shared__ float red[4][16][16];   // 4KB
    int t = threadIdx.x, w = t >> 6, lane = t & 63;
    int col = lane & 15, quad = lane >> 4;
    int b0 = blockIdx.x * 16;
    int k0 = w * 128;
    const float* xr = x + (size_t)(b0 + col) * I_ + k0 + quad * 8;
    unsigned short* xw = xb + (size_t)(b0 + col) * I_ + k0 + quad * 8;
    const unsigned short* bGp = wgt + (size_t)col * I_ + k0 + quad * 8;
    float4_t acc = {0.f, 0.f, 0.f, 0.f};
#pragma unroll
    for (int ks = 0; ks < 128; ks += 32) {
        float4_t xa = *(const float4_t*)(xr + ks);
        float4_t xc = *(const float4_t*)(xr + ks + 4);
        short8 a;
        a[0] = (short)f2bf(xa[0]); a[1] = (short)f2bf(xa[1]);
        a[2] = (short)f2bf(xa[2]); a[3] = (short)f2bf(xa[3]);
        a[4] = (short)f2bf(xc[0]); a[5] = (short)f2bf(xc[1]);
        a[6] = (short)f2bf(xc[2]); a[7] = (short)f2bf(xc[3]);
        *(short8*)(xw + ks) = a;
        short8 b = *(const short8*)(bGp + ks);
        acc = __builtin_amdgcn_mfma_f32_16x16x32_bf16(a, b, acc, 0, 0, 0);
    }
#pragma unroll
    for (int p = 0; p < 4; ++p)
        red[w][quad * 4 + p][col] = acc[p];
    __syncthreads();
    // one thread per (row, te)
    int r = t >> 4, te = t & 15;
    float v = red[0][r][te] + red[1][r][te] + red[2][r][te] + red[3][r][te] + bg[te];
    float m = v;
    m = fmaxf(m, __shfl_xor(m, 1));
    m = fmaxf(m, __shfl_xor(m, 2));
    m = fmaxf(m, __shfl_xor(m, 4));
    float ev = __expf(v - m);
    float s = ev;
    s += __shfl_xor(s, 1);
    s += __shfl_xor(s, 2);
    s += __shfl_xor(s, 4);
    gates[(size_t)te * B_ + b0 + r] = ev / s;
}

// ---------------- layer 1 grouped GEMM: h[e] = relu(xb * w1t[e]^T + b1[e]) bf16 ----------------
// 128x128 tile, BK=64, 4 waves of 64x64, 16x16x32 MFMA, XOR-swizzled LDS.
// Epilogue: bias+relu -> LDS C-tile (aliases As/Bs) -> coalesced short8 stores.
__global__ void gemm_relu_kernel(const unsigned short* __restrict__ A, size_t aSE,
                                 const unsigned short* __restrict__ Bt, size_t bSE,
                                 const float* __restrict__ bias, int biasSE,
                                 unsigned short* __restrict__ C, size_t cSE,
                                 int K, int lda, int ldb, int ldc) {
    __shared__ unsigned short smem[128 * 128];   // 32KB: As | Bs, aliased by C-tile
    unsigned short* As = smem;                    // 128*64
    unsigned short* Bs = smem + 128 * 64;         // 128*64
    int e = blockIdx.z;
    const unsigned short* Ae = A + (size_t)e * aSE;
    const unsigned short* Be = Bt + (size_t)e * bSE;
    const float* biasE = bias + (size_t)e * biasSE;
    unsigned short* Ce = C + (size_t)e * cSE;
    int m0 = blockIdx.x * 128, n0 = blockIdx.y * 128;
    int t = threadIdx.x, w = t >> 6, lane = t & 63;
    int col = lane & 15, quad = lane >> 4;
    int wm = (w & 1) * 64, wn = (w >> 1) * 64;

    float4_t acc[4][4];
#pragma unroll
    for (int mi = 0; mi < 4; ++mi)
#pragma unroll
        for (int ni = 0; ni < 4; ++ni)
            acc[mi][ni] = (float4_t){0.f, 0.f, 0.f, 0.f};

    int rT = t >> 3;
    int gk = (((t & 7) ^ (rT & 7))) * 8;
    const unsigned short* aG = Ae + (size_t)(m0 + rT) * lda + gk;
    const unsigned short* bG = Be + (size_t)(n0 + rT) * ldb + gk;
    unsigned short* aL = As + (size_t)w * 64 * 8;
    unsigned short* bL = Bs + (size_t)w * 64 * 8;

    for (int k0 = 0; k0 < K; k0 += 64) {
#pragma unroll
        for (int j = 0; j < 4; ++j) {
            async_copy16(aG + (size_t)j * 32 * lda + k0, aL + j * 2048);
            async_copy16(bG + (size_t)j * 32 * ldb + k0, bL + j * 2048);
        }
        __syncthreads();
#pragma unroll
        for (int kk = 0; kk < 64; kk += 32) {
            int q = (kk >> 3) + quad;
            short8 af[4], bf[4];
#pragma unroll
            for (int mi = 0; mi < 4; ++mi) {
                int r = wm + mi * 16 + col;
                af[mi] = *(const short8*)&As[r * 64 + ((q ^ (r & 7)) * 8)];
            }
#pragma unroll
            for (int ni = 0; ni < 4; ++ni) {
                int r = wn + ni * 16 + col;
                bf[ni] = *(const short8*)&Bs[r * 64 + ((q ^ (r & 7)) * 8)];
            }
#pragma unroll
            for (int mi = 0; mi < 4; ++mi)
#pragma unroll
                for (int ni = 0; ni < 4; ++ni)
                    acc[mi][ni] = __builtin_amdgcn_mfma_f32_16x16x32_bf16(af[mi], bf[ni], acc[mi][ni], 0, 0, 0);
        }
        __syncthreads();
    }
    // after final barrier all LDS reads are done -> safe to alias as C-tile
    unsigned short* Ct = smem;   // 128 x 128 bf16
#pragma unroll
    for (int ni = 0; ni < 4; ++ni) {
        int c = wn + ni * 16 + col;
        float bv = biasE[n0 + c];
#pragma unroll
        for (int mi = 0; mi < 4; ++mi) {
            int rbase = wm + mi * 16 + quad * 4;
#pragma unroll
            for (int p = 0; p < 4; ++p) {
                float v = acc[mi][ni][p] + bv;
                v = v > 0.f ? v : 0.f;
                Ct[(rbase + p) * 128 + c] = f2bf(v);
            }
        }
    }
    __syncthreads();
    int rr = t >> 4, sl = t & 15;
#pragma unroll
    for (int pass = 0; pass < 8; ++pass) {
        int row = pass * 16 + rr;
        short8 vv = *(const short8*)&Ct[row * 128 + sl * 8];
        *(short8*)&Ce[(size_t)(m0 + row) * ldc + n0 + sl * 8] = vv;
    }
}

// ---------------- fused layer2 + gated combine ----------------
// Tile: 32 rows x 64 cols (N-split 2). LDS 26KB, grid (B/32)x2 = 1024 blocks
// -> 4 blocks/CU, 16 waves/CU for barrier overlap. BK=128.
__global__ void fused_l2_combine_kernel(const unsigned short* __restrict__ h,
                                        const unsigned short* __restrict__ w2t,
                                        const float* __restrict__ b2,
                                        const float* __restrict__ gates,
                                        float* __restrict__ out) {
    __shared__ unsigned short As[32 * 128];   //  8KB: h tile (32 rows x 128 k)
    __shared__ unsigned short Bs[64 * 128];   // 16KB: W2t tile (64 n x 128 k)
    __shared__ float gL[16 * 32];             //  2KB: gates [te][32 rows]

    int b0 = blockIdx.x * 32;
    int nh = blockIdx.y * 64;                 // N-half offset
    int t = threadIdx.x, w = t >> 6, lane = t & 63;
    int col = lane & 15, quad = lane >> 4;
    int wn = w * 16;                          // 4 waves x 16 cols = 64 cols

    if (t < 128) {
        int te = t >> 3, i4 = (t & 7) * 4;
        *(float4_t*)&gL[te * 32 + i4] = *(const float4_t*)&gates[(size_t)te * B_ + b0 + i4];
    }
    // gL first used after first k-loop (contains __syncthreads)

    float4_t tw0[2], tw1[2];
#pragma unroll
    for (int mi = 0; mi < 2; ++mi) {
        tw0[mi] = (float4_t){0.f, 0.f, 0.f, 0.f};
        tw1[mi] = (float4_t){0.f, 0.f, 0.f, 0.f};
    }

    int rT = t >> 4;        // 16 rows per 256-thread issue
    int slot = t & 15;      // 16 slots x 8 shorts = 128-short row

    for (int e = 0; e < E_; ++e) {
        const unsigned short* hE = h + (size_t)e * B_ * H1_;
        const unsigned short* w2E = w2t + (size_t)e * H2_ * H1_ + (size_t)nh * H1_;

        float4_t acc[2];
#pragma unroll
        for (int mi = 0; mi < 2; ++mi)
            acc[mi] = (float4_t){0.f, 0.f, 0.f, 0.f};

        for (int k0 = 0; k0 < H1_; k0 += 128) {
            // stage h tile: 32 rows, 2 issues of 16 rows
#pragma unroll
            for (int j = 0; j < 2; ++j) {
                int row = j * 16 + rT;
                int gk = (((slot ^ row) & 7) | (slot & 8)) * 8;
                async_copy16(hE + (size_t)(b0 + row) * H1_ + k0 + gk,
                             As + j * 2048 + w * 512);
            }
            // stage W2t half-tile: 64 rows, 4 issues of 16 rows
#pragma unroll
            for (int j = 0; j < 4; ++j) {
                int row = j * 16 + rT;
                int gk = (((slot ^ row) & 7) | (slot & 8)) * 8;
                async_copy16(w2E + (size_t)row * H1_ + k0 + gk,
                             Bs + j * 2048 + w * 512);
            }
            __syncthreads();
#pragma unroll
            for (int kk = 0; kk < 128; kk += 32) {
                int q = (kk >> 3) + quad;
                short8 af[2], bfr;
#pragma unroll
                for (int mi = 0; mi < 2; ++mi) {
                    int r = mi * 16 + col;
                    int sw = ((q & 8) | ((q ^ r) & 7)) * 8;
                    af[mi] = *(const short8*)&As[r * 128 + sw];
                }
                {
                    int r = wn + col;
                    int sw = ((q & 8) | ((q ^ r) & 7)) * 8;
                    bfr = *(const short8*)&Bs[r * 128 + sw];
                }
#pragma unroll
                for (int mi = 0; mi < 2; ++mi)
                    acc[mi] = __builtin_amdgcn_mfma_f32_16x16x32_bf16(af[mi], bfr, acc[mi], 0, 0, 0);
            }
            __syncthreads();
        }

        // bias + relu + gated accumulate
        float bv = b2[e * H2_ + nh + wn + col];
#pragma unroll
        for (int mi = 0; mi < 2; ++mi) {
            float4_t g0 = *(const float4_t*)&gL[e * 32 + mi * 16 + quad * 4];        // task 0
            float4_t g1 = *(const float4_t*)&gL[(8 + e) * 32 + mi * 16 + quad * 4];  // task 1
#pragma unroll
            for (int p = 0; p < 4; ++p) {
                float v = acc[mi][p] + bv;
                v = v > 0.f ? v : 0.f;
                tw0[mi][p] += g0[p] * v;
                tw1[mi][p] += g1[p] * v;
            }
        }
    }

    // write out [T][B][H2]
    int n = nh + wn + col;
#pragma unroll
    for (int mi = 0; mi < 2; ++mi) {
#pragma unroll
        for (int p = 0; p < 4; ++p) {
            int r = b0 + mi * 16 + quad * 4 + p;
            out[(size_t)r * H2_ + n] = tw0[mi][p];
            out[(size_t)B_ * H2_ + (size_t)r * H2_ + n] = tw1[mi][p];
        }
    }
}

extern "C" void kernel_launch(void* const* d_in, const int* in_sizes, int n_in,
                              void* d_out, int out_size, void* d_ws, size_t ws_size,
                              hipStream_t stream) {
    const float* x  = (const float*)d_in[0];
    const float* W1 = (const float*)d_in[1];
    const float* b1 = (const float*)d_in[2];
    const float* W2 = (const float*)d_in[3];
    const float* b2 = (const float*)d_in[4];
    const float* Wg = (const float*)d_in[5];
    const float* bg = (const float*)d_in[6];
    float* out = (float*)d_out;

    char* ws = (char*)d_ws;
    unsigned short* xb    = (unsigned short*)(ws);                // 16,777,216 B
    unsigned short* w1t   = (unsigned short*)(ws + 16777216);     //  2,097,152 B
    unsigned short* w2t   = (unsigned short*)(ws + 18874368);     //    524,288 B
    unsigned short* wgt   = (unsigned short*)(ws + 19398656);     //     16,384 B
    float*          gates = (float*)(ws + 19415040);              //  1,048,576 B  [16][B]
    unsigned short* h     = (unsigned short*)(ws + 20463616);     // 67,108,864 B
    // total: 87,572,480 B

    // prep
    transpose_bf16_kernel<<<dim3(H1_ / 32, I_ / 32, E_), dim3(32, 8), 0, stream>>>(W1, w1t, I_, H1_);
    transpose_bf16_kernel<<<dim3(H2_ / 32, H1_ / 32, E_), dim3(32, 8), 0, stream>>>(W2, w2t, H1_, H2_);
    prep_wgt_kernel<<<dim3(T_ * E_ * I_ / 256), 256, 0, stream>>>(Wg, wgt);

    // x->bf16 + gates -> [T*E][B]
    gates_split_kernel<<<dim3(B_ / 16), 256, 0, stream>>>(x, xb, wgt, bg, gates);

    // layer 1: h[e] = relu(xb * w1t[e]^T + b1[e])   M=B, N=H1, K=I
    gemm_relu_kernel<<<dim3(B_ / 128, H1_ / 128, E_), 256, 0, stream>>>(
        xb, 0, w1t, (size_t)H1_ * I_, b1, H1_, h, (size_t)B_ * H1_, I_, I_, I_, H1_);

    // fused layer 2 + combine
    fused_l2_combine_kernel<<<dim3(B_ / 32, 2), 256, 0, stream>>>(h, w2t, b2, gates, out);
}